// Round 1
// baseline (64.143 us; speedup 1.0000x reference)
//
#include <hip/hip_runtime.h>
#include <hip/hip_bf16.h>
#include <stdint.h>

// Problem constants (from reference)
#define IN_F   4096
#define OUT_F  4096
#define NGRP   32
#define NBLK   32
#define GSZ    128
#define OFI    128
#define WPB    1536          // int32 words per (group, out-block) = 3*128*128/32
#define M_TOK  128
#define KSPLIT 8

typedef __attribute__((ext_vector_type(8))) short bf16x8;
typedef __attribute__((ext_vector_type(4))) float f32x4;

static __device__ __forceinline__ unsigned short f2bf(float f) {
    union { float f; uint32_t u; } v; v.f = f;
    uint32_t r = v.u + 0x7fffu + ((v.u >> 16) & 1u);   // round-to-nearest-even
    return (unsigned short)(r >> 16);
}

// ---------------------------------------------------------------------------
// Kernel 1: xr[t][i] = bf16(x[t][in_reorder[i]])   (128 x 4096)
// ---------------------------------------------------------------------------
__global__ __launch_bounds__(256) void k_xr(const float* __restrict__ x,
                                            const int* __restrict__ in_reorder,
                                            unsigned short* __restrict__ xr) {
    int idx = blockIdx.x * 256 + threadIdx.x;   // 0 .. 524287
    int t = idx >> 12;
    int i = idx & 4095;
    int src = in_reorder[i];
    xr[idx] = f2bf(x[t * IN_F + src]);
}

// ---------------------------------------------------------------------------
// Kernel 2: dequant qweight -> WT[N][K] bf16 (transposed weight, N-major)
//   WT[n*128+o][g*128+io] = (2b0+4b1+8b2-7)*alpha[g][n*128+o] + beta[g][n*128+o]
//   word for bit (io,o) of block (g,n): base + b*512 + io*4 + (o>>5), bit o&31
// One block per (g,n). Wave w owns o in [w*32, w*32+32); lane l owns io=2l,2l+1.
// ---------------------------------------------------------------------------
__global__ __launch_bounds__(256) void k_dequant(const int* __restrict__ qweight,
                                                 const float* __restrict__ alpha,
                                                 const float* __restrict__ beta,
                                                 const int* __restrict__ offset,
                                                 unsigned short* __restrict__ WT) {
    int gb = blockIdx.x;              // g*NBLK + n
    int g = gb >> 5, n = gb & 31;
    int w = threadIdx.x >> 6;         // wave id 0..3  -> o>>5
    int l = threadIdx.x & 63;         // lane -> io = 2l, 2l+1
    const int* q = qweight + offset[gb] + w;
    int io0 = 2 * l;
    // hoist the 6 words this lane needs (3 planes x 2 io rows)
    int w00 = q[ io0      * 4];
    int w01 = q[(io0 + 1) * 4];
    int w10 = q[ io0      * 4 + 512];
    int w11 = q[(io0 + 1) * 4 + 512];
    int w20 = q[ io0      * 4 + 1024];
    int w21 = q[(io0 + 1) * 4 + 1024];
    const float* arow = alpha + g * OUT_F + n * OFI + w * 32;
    const float* brow = beta  + g * OUT_F + n * OFI + w * 32;
    unsigned short* wbase = WT + (size_t)(n * OFI + w * 32) * IN_F + g * GSZ + io0;
    #pragma unroll 8
    for (int j = 0; j < 32; ++j) {
        float a  = arow[j];
        float bt = brow[j];
        int q0 = ((w00 >> j) & 1) * 2 + ((w10 >> j) & 1) * 4 + ((w20 >> j) & 1) * 8 - 7;
        int q1 = ((w01 >> j) & 1) * 2 + ((w11 >> j) & 1) * 4 + ((w21 >> j) & 1) * 8 - 7;
        float v0 = (float)q0 * a + bt;
        float v1 = (float)q1 * a + bt;
        unsigned int pack = (unsigned int)f2bf(v0) | ((unsigned int)f2bf(v1) << 16);
        *(unsigned int*)(wbase + (size_t)j * IN_F) = pack;
    }
}

// ---------------------------------------------------------------------------
// Kernel 3: split-K bf16 MFMA GEMM.
//   Cpart[ks][t][c] = sum_{k in ks-chunk} xr[t][k] * WT[c][k]
// Block: 256 threads (4 waves as 2x2), tile 128 rows x 128 cols, BK=64.
// Grid: (32 n-blocks, 8 k-splits) = 256 blocks.
// ---------------------------------------------------------------------------
__global__ __launch_bounds__(256) void k_gemm(const unsigned short* __restrict__ xr,
                                              const unsigned short* __restrict__ WT,
                                              float* __restrict__ Cpart) {
    __shared__ unsigned short Alds[128 * 64];
    __shared__ unsigned short Blds[128 * 64];
    const int n0  = blockIdx.x * 128;
    const int ks  = blockIdx.y;
    const int tid = threadIdx.x;
    const int l   = tid & 63;
    const int wid = tid >> 6;
    const int wm  = wid >> 1, wn = wid & 1;

    f32x4 acc[4][4] = {};

    for (int kt = 0; kt < 8; ++kt) {
        const int k0 = ks * 512 + kt * 64;
        #pragma unroll
        for (int qc = 0; qc < 4; ++qc) {
            int e   = (qc * 256 + tid) * 8;    // linear bf16 element in 128x64 tile
            int row = e >> 6;
            int col = e & 63;
            *(uint4*)&Alds[e] = *(const uint4*)&xr[(size_t)row * IN_F + k0 + col];
            *(uint4*)&Blds[e] = *(const uint4*)&WT[(size_t)(n0 + row) * IN_F + k0 + col];
        }
        __syncthreads();
        #pragma unroll
        for (int kk = 0; kk < 2; ++kk) {
            bf16x8 af[4], bfr[4];
            const int colb = kk * 32 + (l >> 4) * 8;
            #pragma unroll
            for (int m = 0; m < 4; ++m)
                af[m] = *(const bf16x8*)&Alds[(wm * 64 + m * 16 + (l & 15)) * 64 + colb];
            #pragma unroll
            for (int nn = 0; nn < 4; ++nn)
                bfr[nn] = *(const bf16x8*)&Blds[(wn * 64 + nn * 16 + (l & 15)) * 64 + colb];
            #pragma unroll
            for (int m = 0; m < 4; ++m)
                #pragma unroll
                for (int nn = 0; nn < 4; ++nn)
                    acc[m][nn] = __builtin_amdgcn_mfma_f32_16x16x32_bf16(
                        af[m], bfr[nn], acc[m][nn], 0, 0, 0);
        }
        __syncthreads();
    }

    float* Cb = Cpart + (size_t)ks * (M_TOK * OUT_F);
    #pragma unroll
    for (int m = 0; m < 4; ++m) {
        int row = wm * 64 + m * 16 + ((l >> 4) << 2);
        #pragma unroll
        for (int nn = 0; nn < 4; ++nn) {
            int col = n0 + wn * 64 + nn * 16 + (l & 15);
            #pragma unroll
            for (int r = 0; r < 4; ++r)
                Cb[(size_t)(row + r) * OUT_F + col] = acc[m][nn][r];
        }
    }
}

// ---------------------------------------------------------------------------
// Kernel 4: out[t][jj] = sum_ks Cpart[ks][t][out_reorder[jj]]  (fixed order -> deterministic)
// ---------------------------------------------------------------------------
__global__ __launch_bounds__(256) void k_reduce(const float* __restrict__ Cpart,
                                                const int* __restrict__ out_reorder,
                                                float* __restrict__ out) {
    int idx = blockIdx.x * 256 + threadIdx.x;   // 0 .. 524287
    int t  = idx >> 12;
    int jj = idx & 4095;
    int c  = out_reorder[jj];
    float s = 0.0f;
    #pragma unroll
    for (int ks = 0; ks < KSPLIT; ++ks)
        s += Cpart[(size_t)ks * (M_TOK * OUT_F) + (size_t)t * OUT_F + c];
    out[idx] = s;
}

// ---------------------------------------------------------------------------
extern "C" void kernel_launch(void* const* d_in, const int* in_sizes, int n_in,
                              void* d_out, int out_size, void* d_ws, size_t ws_size,
                              hipStream_t stream) {
    const float* x           = (const float*)d_in[0];
    const int*   qweight     = (const int*)d_in[1];
    const float* alpha       = (const float*)d_in[2];
    const float* beta        = (const float*)d_in[3];
    // d_in[4] = block_bitwidth (uniform 3, unused)
    const int*   offset      = (const int*)d_in[5];
    const int*   in_reorder  = (const int*)d_in[6];
    const int*   out_reorder = (const int*)d_in[7];
    float* out = (float*)d_out;

    // workspace layout: WT (32MB) | xr (1MB) | Cpart (16MB)  = 49MB
    unsigned short* WT    = (unsigned short*)d_ws;
    unsigned short* xr    = (unsigned short*)((char*)d_ws + 33554432);
    float*          Cpart = (float*)((char*)d_ws + 34603008);

    k_xr<<<dim3(2048), dim3(256), 0, stream>>>(x, in_reorder, xr);
    k_dequant<<<dim3(NGRP * NBLK), dim3(256), 0, stream>>>(qweight, alpha, beta, offset, WT);
    k_gemm<<<dim3(32, KSPLIT), dim3(256), 0, stream>>>(xr, WT, Cpart);
    k_reduce<<<dim3(2048), dim3(256), 0, stream>>>(Cpart, out_reorder, out);
}

// Round 2
// 53.974 us; speedup vs baseline: 1.1884x; 1.1884x over previous
//
#include <hip/hip_runtime.h>
#include <hip/hip_bf16.h>
#include <stdint.h>

// Problem constants (from reference)
#define IN_F   4096
#define OUT_F  4096
#define NGRP   32
#define NBLK   32
#define GSZ    128
#define OFI    128
#define WPB    1536          // int32 words per (group, out-block)
#define M_TOK  128
#define KSPLIT 8

typedef __attribute__((ext_vector_type(8))) short bf16x8;
typedef __attribute__((ext_vector_type(4))) float f32x4;

static __device__ __forceinline__ unsigned short f2bf(float f) {
    union { float f; uint32_t u; } v; v.f = f;
    uint32_t r = v.u + 0x7fffu + ((v.u >> 16) & 1u);   // RNE
    return (unsigned short)(r >> 16);
}

// ---------------------------------------------------------------------------
// Kernel 1: xr[t][i] = bf16(x[t][in_reorder[i]])   (128 x 4096)
// ---------------------------------------------------------------------------
__global__ __launch_bounds__(256) void k_xr(const float* __restrict__ x,
                                            const int* __restrict__ in_reorder,
                                            unsigned short* __restrict__ xr) {
    int idx = blockIdx.x * 256 + threadIdx.x;   // 0 .. 524287
    int t = idx >> 12;
    int i = idx & 4095;
    int src = in_reorder[i];
    xr[idx] = f2bf(x[t * IN_F + src]);
}

// ---------------------------------------------------------------------------
// Kernel 2 (fused): dequant + split-K bf16 MFMA GEMM.
//   Cpart[ks][t][c] = sum_{k in ks-chunk} xr[t][k] * W[k][c]
// Block: 512 threads (8 waves as 2m x 4n), out tile 128 x 128, BK=128 (one
// quant group per K-step). B-tile is dequantized from qweight straight into
// swizzled LDS; A-tile staged from xr into swizzled LDS.
// Grid: (32 n-blocks, 8 k-splits) = 256 blocks, 1 block/CU, 2 waves/SIMD.
//
// LDS swizzle (both tiles, [row][128] bf16): 16B-block col index cb (0..15)
// stored at cb ^ (row & 15)  ->  ds_read_b128 across 16 rows at fixed cb hits
// 16 distinct cb' -> <=2-way bank alias (free).
// ---------------------------------------------------------------------------
__global__ __launch_bounds__(512) void k_fused(const unsigned short* __restrict__ xr,
                                               const int* __restrict__ qweight,
                                               const float* __restrict__ alpha,
                                               const float* __restrict__ beta,
                                               const int* __restrict__ offset,
                                               float* __restrict__ Cpart) {
    __shared__ unsigned short Alds[128 * 128];   // [token][k]   32 KB
    __shared__ unsigned short Blds[128 * 128];   // [col][k]     32 KB
    const int nb  = blockIdx.x;            // 0..31
    const int ks  = blockIdx.y;            // 0..7
    const int n0  = nb * OFI;
    const int tid = threadIdx.x;
    const int l   = tid & 63;
    const int wid = tid >> 6;              // 0..7
    const int wm  = wid >> 2;              // 0..1  (row half)
    const int wn  = wid & 3;               // 0..3  (col quarter)

    // dequant role: wave -> (word-col wc, bit-half h); lane -> io pair (2l, 2l+1)
    const int wc  = wid >> 1;              // 0..3  -> cols [32*wc, 32*wc+32)
    const int h   = wid & 1;               // bit half: bits 16h..16h+15
    const int io0 = 2 * l;

    f32x4 acc[4][2] = {};

    for (int kt = 0; kt < 4; ++kt) {
        const int g  = ks * 4 + kt;        // quant group = K-chunk of 128
        const int k0 = g * GSZ;

        // ---- stage A: 128x128 bf16, swizzled ----
        #pragma unroll
        for (int p = 0; p < 4; ++p) {
            int e   = (p * 512 + tid) * 8;       // linear elem in tile
            int row = e >> 7;
            int col = e & 127;
            int cb  = col >> 3;
            uint4 v = *(const uint4*)&xr[(size_t)row * IN_F + k0 + col];
            *(uint4*)&Alds[row * 128 + ((cb ^ (row & 15)) << 3)] = v;
        }

        // ---- dequant B: group g, this block's 128 cols -> swizzled LDS ----
        {
            const int gb = g * NBLK + nb;
            const int* q = qweight + offset[gb] + wc;
            int w00 = q[ io0      * 4];
            int w01 = q[(io0 + 1) * 4];
            int w10 = q[ io0      * 4 + 512];
            int w11 = q[(io0 + 1) * 4 + 512];
            int w20 = q[ io0      * 4 + 1024];
            int w21 = q[(io0 + 1) * 4 + 1024];
            const float* arow = alpha + g * OUT_F + n0 + wc * 32 + h * 16;
            const float* brow = beta  + g * OUT_F + n0 + wc * 32 + h * 16;
            const int cbB = io0 >> 3;            // = l>>2
            #pragma unroll
            for (int j = 0; j < 16; ++j) {
                int jb   = h * 16 + j;           // bit index in word
                int col  = wc * 32 + h * 16 + j; // local out col
                float a  = arow[j];
                float bt = brow[j];
                int q0 = ((w00 >> jb) & 1) * 2 + ((w10 >> jb) & 1) * 4 + ((w20 >> jb) & 1) * 8 - 7;
                int q1 = ((w01 >> jb) & 1) * 2 + ((w11 >> jb) & 1) * 4 + ((w21 >> jb) & 1) * 8 - 7;
                unsigned int pack = (unsigned int)f2bf((float)q0 * a + bt)
                                  | ((unsigned int)f2bf((float)q1 * a + bt) << 16);
                *(unsigned int*)&Blds[col * 128 + ((cbB ^ (col & 15)) << 3) + (io0 & 7)] = pack;
            }
        }
        __syncthreads();

        // ---- MFMA over the 128-K tile ----
        #pragma unroll
        for (int kk = 0; kk < 4; ++kk) {
            const int cb = kk * 4 + (l >> 4);
            bf16x8 af[4], bfr[2];
            #pragma unroll
            for (int m = 0; m < 4; ++m) {
                int row = wm * 64 + m * 16 + (l & 15);
                af[m] = *(const bf16x8*)&Alds[row * 128 + ((cb ^ (row & 15)) << 3)];
            }
            #pragma unroll
            for (int nn = 0; nn < 2; ++nn) {
                int cl = wn * 32 + nn * 16 + (l & 15);
                bfr[nn] = *(const bf16x8*)&Blds[cl * 128 + ((cb ^ (cl & 15)) << 3)];
            }
            #pragma unroll
            for (int m = 0; m < 4; ++m)
                #pragma unroll
                for (int nn = 0; nn < 2; ++nn)
                    acc[m][nn] = __builtin_amdgcn_mfma_f32_16x16x32_bf16(
                        af[m], bfr[nn], acc[m][nn], 0, 0, 0);
        }
        __syncthreads();
    }

    // ---- epilogue: per-wave 64x32 tile -> Cpart[ks] ----
    float* Cb = Cpart + (size_t)ks * (M_TOK * OUT_F);
    #pragma unroll
    for (int m = 0; m < 4; ++m) {
        int row = wm * 64 + m * 16 + ((l >> 4) << 2);
        #pragma unroll
        for (int nn = 0; nn < 2; ++nn) {
            int col = n0 + wn * 32 + nn * 16 + (l & 15);
            #pragma unroll
            for (int r = 0; r < 4; ++r)
                Cb[(size_t)(row + r) * OUT_F + col] = acc[m][nn][r];
        }
    }
}

// ---------------------------------------------------------------------------
// Kernel 3: out[t][jj] = sum_ks Cpart[ks][t][out_reorder[jj]]  (deterministic)
// ---------------------------------------------------------------------------
__global__ __launch_bounds__(256) void k_reduce(const float* __restrict__ Cpart,
                                                const int* __restrict__ out_reorder,
                                                float* __restrict__ out) {
    int idx = blockIdx.x * 256 + threadIdx.x;   // 0 .. 524287
    int t  = idx >> 12;
    int jj = idx & 4095;
    int c  = out_reorder[jj];
    float s = 0.0f;
    #pragma unroll
    for (int ks = 0; ks < KSPLIT; ++ks)
        s += Cpart[(size_t)ks * (M_TOK * OUT_F) + (size_t)t * OUT_F + c];
    out[idx] = s;
}

// ---------------------------------------------------------------------------
extern "C" void kernel_launch(void* const* d_in, const int* in_sizes, int n_in,
                              void* d_out, int out_size, void* d_ws, size_t ws_size,
                              hipStream_t stream) {
    const float* x           = (const float*)d_in[0];
    const int*   qweight     = (const int*)d_in[1];
    const float* alpha       = (const float*)d_in[2];
    const float* beta        = (const float*)d_in[3];
    // d_in[4] = block_bitwidth (uniform 3, unused)
    const int*   offset      = (const int*)d_in[5];
    const int*   in_reorder  = (const int*)d_in[6];
    const int*   out_reorder = (const int*)d_in[7];
    float* out = (float*)d_out;

    // workspace: xr (1MB) | Cpart (16MB)
    unsigned short* xr    = (unsigned short*)d_ws;
    float*          Cpart = (float*)((char*)d_ws + 1048576);

    k_xr<<<dim3(2048), dim3(256), 0, stream>>>(x, in_reorder, xr);
    k_fused<<<dim3(32, KSPLIT), dim3(512), 0, stream>>>(xr, qweight, alpha, beta, offset, Cpart);
    k_reduce<<<dim3(2048), dim3(256), 0, stream>>>(Cpart, out_reorder, out);
}

// Round 3
// 45.737 us; speedup vs baseline: 1.4024x; 1.1801x over previous
//
#include <hip/hip_runtime.h>
#include <hip/hip_bf16.h>
#include <stdint.h>

// Problem constants (from reference)
#define IN_F   4096
#define OUT_F  4096
#define NGRP   32
#define NBLK   32
#define GSZ    128
#define OFI    128
#define WPB    1536          // int32 words per (group, out-block)
#define M_TOK  128
#define KSPLIT 8

typedef __attribute__((ext_vector_type(8))) short bf16x8;
typedef __attribute__((ext_vector_type(4))) float f32x4;

static __device__ __forceinline__ unsigned short f2bf(float f) {
    union { float f; uint32_t u; } v; v.f = f;
    uint32_t r = v.u + 0x7fffu + ((v.u >> 16) & 1u);   // RNE
    return (unsigned short)(r >> 16);
}

// ---------------------------------------------------------------------------
// Kernel 0: invert both permutations.  inv[p[i]] = i
// ---------------------------------------------------------------------------
__global__ __launch_bounds__(256) void k_inv(const int* __restrict__ in_reorder,
                                             const int* __restrict__ out_reorder,
                                             int* __restrict__ inv_in,
                                             int* __restrict__ inv_out) {
    int i = blockIdx.x * 256 + threadIdx.x;   // 0..4095
    inv_in[in_reorder[i]]   = i;
    inv_out[out_reorder[i]] = i;
}

// ---------------------------------------------------------------------------
// Kernel 1: xr[t][inv_in[s]] = bf16(x[t][s])  — coalesced read, scatter write
// ---------------------------------------------------------------------------
__global__ __launch_bounds__(256) void k_xr(const float* __restrict__ x,
                                            const int* __restrict__ inv_in,
                                            unsigned short* __restrict__ xr) {
    int idx = blockIdx.x * 256 + threadIdx.x;   // 0..131071, 4 elems each
    int t  = idx >> 10;
    int s0 = (idx & 1023) << 2;
    float4 v = *(const float4*)&x[(size_t)t * IN_F + s0];
    const int* ip = &inv_in[s0];
    unsigned short* row = xr + (size_t)t * IN_F;
    row[ip[0]] = f2bf(v.x);
    row[ip[1]] = f2bf(v.y);
    row[ip[2]] = f2bf(v.z);
    row[ip[3]] = f2bf(v.w);
}

// ---------------------------------------------------------------------------
// Kernel 2 (fused): dequant + split-K bf16 MFMA GEMM.  (unchanged, known-good)
//   Cpart[ks][t][c] = sum_{k in ks-chunk} xr[t][k] * W[k][c]
// ---------------------------------------------------------------------------
__global__ __launch_bounds__(512) void k_fused(const unsigned short* __restrict__ xr,
                                               const int* __restrict__ qweight,
                                               const float* __restrict__ alpha,
                                               const float* __restrict__ beta,
                                               const int* __restrict__ offset,
                                               float* __restrict__ Cpart) {
    __shared__ unsigned short Alds[128 * 128];   // [token][k]   32 KB
    __shared__ unsigned short Blds[128 * 128];   // [col][k]     32 KB
    const int nb  = blockIdx.x;            // 0..31
    const int ks  = blockIdx.y;            // 0..7
    const int n0  = nb * OFI;
    const int tid = threadIdx.x;
    const int l   = tid & 63;
    const int wid = tid >> 6;              // 0..7
    const int wm  = wid >> 2;              // 0..1  (row half)
    const int wn  = wid & 3;               // 0..3  (col quarter)

    // dequant role: wave -> (word-col wc, bit-half h); lane -> io pair (2l, 2l+1)
    const int wc  = wid >> 1;              // 0..3
    const int h   = wid & 1;               // bit half
    const int io0 = 2 * l;

    f32x4 acc[4][2] = {};

    for (int kt = 0; kt < 4; ++kt) {
        const int g  = ks * 4 + kt;        // quant group
        const int k0 = g * GSZ;

        // ---- stage A: 128x128 bf16, swizzled ----
        #pragma unroll
        for (int p = 0; p < 4; ++p) {
            int e   = (p * 512 + tid) * 8;
            int row = e >> 7;
            int col = e & 127;
            int cb  = col >> 3;
            uint4 v = *(const uint4*)&xr[(size_t)row * IN_F + k0 + col];
            *(uint4*)&Alds[row * 128 + ((cb ^ (row & 15)) << 3)] = v;
        }

        // ---- dequant B: group g, this block's 128 cols -> swizzled LDS ----
        {
            const int gb = g * NBLK + nb;
            const int* q = qweight + offset[gb] + wc;
            int w00 = q[ io0      * 4];
            int w01 = q[(io0 + 1) * 4];
            int w10 = q[ io0      * 4 + 512];
            int w11 = q[(io0 + 1) * 4 + 512];
            int w20 = q[ io0      * 4 + 1024];
            int w21 = q[(io0 + 1) * 4 + 1024];
            const float* arow = alpha + g * OUT_F + n0 + wc * 32 + h * 16;
            const float* brow = beta  + g * OUT_F + n0 + wc * 32 + h * 16;
            const int cbB = io0 >> 3;
            #pragma unroll
            for (int j = 0; j < 16; ++j) {
                int jb   = h * 16 + j;
                int col  = wc * 32 + h * 16 + j;
                float a  = arow[j];
                float bt = brow[j];
                int q0 = ((w00 >> jb) & 1) * 2 + ((w10 >> jb) & 1) * 4 + ((w20 >> jb) & 1) * 8 - 7;
                int q1 = ((w01 >> jb) & 1) * 2 + ((w11 >> jb) & 1) * 4 + ((w21 >> jb) & 1) * 8 - 7;
                unsigned int pack = (unsigned int)f2bf((float)q0 * a + bt)
                                  | ((unsigned int)f2bf((float)q1 * a + bt) << 16);
                *(unsigned int*)&Blds[col * 128 + ((cbB ^ (col & 15)) << 3) + (io0 & 7)] = pack;
            }
        }
        __syncthreads();

        // ---- MFMA over the 128-K tile ----
        #pragma unroll
        for (int kk = 0; kk < 4; ++kk) {
            const int cb = kk * 4 + (l >> 4);
            bf16x8 af[4], bfr[2];
            #pragma unroll
            for (int m = 0; m < 4; ++m) {
                int row = wm * 64 + m * 16 + (l & 15);
                af[m] = *(const bf16x8*)&Alds[row * 128 + ((cb ^ (row & 15)) << 3)];
            }
            #pragma unroll
            for (int nn = 0; nn < 2; ++nn) {
                int cl = wn * 32 + nn * 16 + (l & 15);
                bfr[nn] = *(const bf16x8*)&Blds[cl * 128 + ((cb ^ (cl & 15)) << 3)];
            }
            #pragma unroll
            for (int m = 0; m < 4; ++m)
                #pragma unroll
                for (int nn = 0; nn < 2; ++nn)
                    acc[m][nn] = __builtin_amdgcn_mfma_f32_16x16x32_bf16(
                        af[m], bfr[nn], acc[m][nn], 0, 0, 0);
        }
        __syncthreads();
    }

    // ---- epilogue: per-wave 64x32 tile -> Cpart[ks] ----
    float* Cb = Cpart + (size_t)ks * (M_TOK * OUT_F);
    #pragma unroll
    for (int m = 0; m < 4; ++m) {
        int row = wm * 64 + m * 16 + ((l >> 4) << 2);
        #pragma unroll
        for (int nn = 0; nn < 2; ++nn) {
            int col = n0 + wn * 32 + nn * 16 + (l & 15);
            #pragma unroll
            for (int r = 0; r < 4; ++r)
                Cb[(size_t)(row + r) * OUT_F + col] = acc[m][nn][r];
        }
    }
}

// ---------------------------------------------------------------------------
// Kernel 3: out[t][inv_out[c]] = sum_ks Cpart[ks][t][c]
//   coalesced float4 reads, scattered 4B writes (L2 merges lines).
// ---------------------------------------------------------------------------
__global__ __launch_bounds__(256) void k_reduce(const float* __restrict__ Cpart,
                                                const int* __restrict__ inv_out,
                                                float* __restrict__ out) {
    int idx = blockIdx.x * 256 + threadIdx.x;   // 0..131071, 4 cols each
    int t  = idx >> 10;
    int c0 = (idx & 1023) << 2;
    float4 s = make_float4(0.f, 0.f, 0.f, 0.f);
    #pragma unroll
    for (int ks = 0; ks < KSPLIT; ++ks) {
        float4 v = *(const float4*)&Cpart[(size_t)ks * (M_TOK * OUT_F) + (size_t)t * OUT_F + c0];
        s.x += v.x; s.y += v.y; s.z += v.z; s.w += v.w;
    }
    const int* op = &inv_out[c0];
    float* row = out + (size_t)t * OUT_F;
    row[op[0]] = s.x;
    row[op[1]] = s.y;
    row[op[2]] = s.z;
    row[op[3]] = s.w;
}

// ---------------------------------------------------------------------------
extern "C" void kernel_launch(void* const* d_in, const int* in_sizes, int n_in,
                              void* d_out, int out_size, void* d_ws, size_t ws_size,
                              hipStream_t stream) {
    const float* x           = (const float*)d_in[0];
    const int*   qweight     = (const int*)d_in[1];
    const float* alpha       = (const float*)d_in[2];
    const float* beta        = (const float*)d_in[3];
    // d_in[4] = block_bitwidth (uniform 3, unused)
    const int*   offset      = (const int*)d_in[5];
    const int*   in_reorder  = (const int*)d_in[6];
    const int*   out_reorder = (const int*)d_in[7];
    float* out = (float*)d_out;

    // workspace: xr (1MB) | Cpart (16MB) | inv_in (16KB) | inv_out (16KB)
    unsigned short* xr     = (unsigned short*)d_ws;
    float*          Cpart  = (float*)((char*)d_ws + 1048576);
    int*            inv_in = (int*)((char*)d_ws + 1048576 + 16777216);
    int*            inv_out= inv_in + IN_F;

    k_inv<<<dim3(16), dim3(256), 0, stream>>>(in_reorder, out_reorder, inv_in, inv_out);
    k_xr<<<dim3(512), dim3(256), 0, stream>>>(x, inv_in, xr);
    k_fused<<<dim3(32, KSPLIT), dim3(512), 0, stream>>>(xr, qweight, alpha, beta, offset, Cpart);
    k_reduce<<<dim3(512), dim3(256), 0, stream>>>(Cpart, inv_out, out);
}

// Round 4
// 31.559 us; speedup vs baseline: 2.0325x; 1.4493x over previous
//
#include <hip/hip_runtime.h>
#include <hip/hip_bf16.h>
#include <stdint.h>

// Problem constants (from reference)
#define IN_F   4096
#define OUT_F  4096
#define NGRP   32
#define NBLK   32
#define GSZ    128
#define OFI    128
#define WPB    1536          // int32 words per (group, out-block)
#define M_TOK  128
#define KSPLIT 8
#define NTILE  64            // columns per GEMM block

typedef __attribute__((ext_vector_type(8))) short bf16x8;
typedef __attribute__((ext_vector_type(4))) float f32x4;

// one-instruction packed f32x2 -> bf16x2 (RNE), gfx950
static __device__ __forceinline__ unsigned cvt_pk_bf16(float lo, float hi) {
    unsigned r;
    asm("v_cvt_pk_bf16_f32 %0, %1, %2" : "=v"(r) : "v"(lo), "v"(hi));
    return r;
}

// ---------------------------------------------------------------------------
// Prep kernel (3 roles by blockIdx.x):
//   [0,512):    xr[t][i] = bf16(x[t][in_reorder[i]])   gather-read, coalesced write
//   [512,516):  inv_out[out_reorder[i]] = i
//   [516,644):  A2 = 2*alpha ; B7 = beta - 7*alpha
// ---------------------------------------------------------------------------
__global__ __launch_bounds__(256) void k_prep(const float* __restrict__ x,
                                              const int* __restrict__ in_reorder,
                                              const int* __restrict__ out_reorder,
                                              const float* __restrict__ alpha,
                                              const float* __restrict__ beta,
                                              unsigned short* __restrict__ xr,
                                              int* __restrict__ inv_out,
                                              float* __restrict__ A2,
                                              float* __restrict__ B7) {
    int b = blockIdx.x;
    if (b < 512) {
        int idx = b * 256 + threadIdx.x;          // 0..131071, 4 elems each
        int t  = idx >> 10;
        int i0 = (idx & 1023) << 2;
        int4 src = *(const int4*)&in_reorder[i0];
        const float* row = x + (size_t)t * IN_F;
        float v0 = row[src.x], v1 = row[src.y], v2 = row[src.z], v3 = row[src.w];
        uint2 pk;
        pk.x = cvt_pk_bf16(v0, v1);
        pk.y = cvt_pk_bf16(v2, v3);
        *(uint2*)&xr[(size_t)t * IN_F + i0] = pk;
    } else if (b < 516) {
        int i0 = ((b - 512) * 256 + threadIdx.x) << 2;   // 0..4095 step 4
        int4 o = *(const int4*)&out_reorder[i0];
        inv_out[o.x] = i0;
        inv_out[o.y] = i0 + 1;
        inv_out[o.z] = i0 + 2;
        inv_out[o.w] = i0 + 3;
    } else {
        int idx = ((b - 516) * 256 + threadIdx.x) << 2;  // 0..131068 step 4
        float4 a = *(const float4*)&alpha[idx];
        float4 bt = *(const float4*)&beta[idx];
        float4 a2 = make_float4(2.f * a.x, 2.f * a.y, 2.f * a.z, 2.f * a.w);
        float4 b7 = make_float4(bt.x - 7.f * a.x, bt.y - 7.f * a.y,
                                bt.z - 7.f * a.z, bt.w - 7.f * a.w);
        *(float4*)&A2[idx] = a2;
        *(float4*)&B7[idx] = b7;
    }
}

// ---------------------------------------------------------------------------
// Fused dequant + split-K bf16 MFMA GEMM.
//   Cpart[ks][t][c] = sum_{k in ks-chunk} xr[t][k] * W[k][c]
// Block: 256 threads (4 waves as 2m x 2n), tile 128 x 64, BK=128 (one quant
// group per K-step), grid (64 nb, 8 ks) = 512 blocks -> 2 blocks/CU.
// LDS: A 128x128 bf16 (32KB) + B 64x128 bf16 (16KB), both XOR-swizzled:
//   elem(row,k) = row*128 + (((k>>3) ^ (row&15))<<3) + (k&7)
// ---------------------------------------------------------------------------
__global__ __launch_bounds__(256, 2) void k_fused(const unsigned short* __restrict__ xr,
                                                  const int* __restrict__ qweight,
                                                  const float* __restrict__ A2,
                                                  const float* __restrict__ B7,
                                                  const int* __restrict__ offset,
                                                  float* __restrict__ Cpart) {
    __shared__ unsigned short Alds[128 * 128];   // 32 KB
    __shared__ unsigned short Blds[NTILE * 128]; // 16 KB
    const int nb  = blockIdx.x;            // 0..63
    const int ks  = blockIdx.y;            // 0..7
    const int n   = nb >> 1;               // 128-col out-block
    const int wcb = (nb & 1) * 2;          // word-quarter base (0 or 2)
    const int n0  = nb * NTILE;            // global col base
    const int tid = threadIdx.x;
    const int l   = tid & 63;
    const int wid = tid >> 6;              // 0..3
    const int wm  = wid >> 1;              // row half
    const int wn  = wid & 1;               // col half

    // dequant role: io-pair p, word-quarter wc (0/1 within our 64 cols), col-half h
    const int p  = tid >> 2;               // 0..63  -> io = 2p, 2p+1
    const int wc = (tid >> 1) & 1;
    const int h  = tid & 1;
    const int wq = wcb + wc;                // word quarter 0..3
    const int io0 = 2 * p;

    f32x4 acc[4][2] = {};

    // prefetch K-tile 0's qweight words
    int cw0a, cw0b, cw1a, cw1b, cw2a, cw2b;
    {
        const int gb0 = (ks * 4) * NBLK + n;
        const int* q = qweight + offset[gb0];
        cw0a = q[ io0      * 4 + wq];
        cw0b = q[(io0 + 1) * 4 + wq];
        cw1a = q[ io0      * 4 + wq + 512];
        cw1b = q[(io0 + 1) * 4 + wq + 512];
        cw2a = q[ io0      * 4 + wq + 1024];
        cw2b = q[(io0 + 1) * 4 + wq + 1024];
    }

    #pragma unroll
    for (int kt = 0; kt < 4; ++kt) {
        const int g  = ks * 4 + kt;        // quant group
        const int k0 = g * GSZ;

        // ---- stage A: 128x128 bf16, coalesced read -> swizzled LDS write ----
        #pragma unroll
        for (int c = 0; c < 8; ++c) {
            int e   = (c * 256 + tid) * 8;
            int row = e >> 7;
            int cb  = (e >> 3) & 15;
            uint4 v = *(const uint4*)&xr[(size_t)row * IN_F + k0 + (cb << 3)];
            *(uint4*)&Alds[row * 128 + ((cb ^ (row & 15)) << 3)] = v;
        }

        // ---- dequant B: 64 cols x 128 io -> swizzled LDS ----
        {
            const float* a2 = A2 + g * OUT_F + n0 + wc * 32 + h * 16;
            const float* b7 = B7 + g * OUT_F + n0 + wc * 32 + h * 16;
            unsigned* B32 = (unsigned*)Blds;
            #pragma unroll
            for (int j = 0; j < 16; ++j) {
                int jb  = h * 16 + j;              // bit index in word
                int col = wc * 32 + jb;            // local col 0..63
                float sa = a2[j];
                float sb = b7[j];
                int na = ((cw0a >> jb) & 1) | (((cw1a >> jb) & 1) << 1) | (((cw2a >> jb) & 1) << 2);
                int nbq = ((cw0b >> jb) & 1) | (((cw1b >> jb) & 1) << 1) | (((cw2b >> jb) & 1) << 2);
                float va = (float)na  * sa + sb;
                float vb = (float)nbq * sa + sb;
                B32[col * 64 + (((p >> 2) ^ (col & 15)) << 2) + (p & 3)] = cvt_pk_bf16(va, vb);
            }
        }

        // ---- prefetch next K-tile's words (hides HBM latency under MFMA) ----
        if (kt < 3) {
            const int gb1 = (ks * 4 + kt + 1) * NBLK + n;
            const int* q = qweight + offset[gb1];
            cw0a = q[ io0      * 4 + wq];
            cw0b = q[(io0 + 1) * 4 + wq];
            cw1a = q[ io0      * 4 + wq + 512];
            cw1b = q[(io0 + 1) * 4 + wq + 512];
            cw2a = q[ io0      * 4 + wq + 1024];
            cw2b = q[(io0 + 1) * 4 + wq + 1024];
        }
        __syncthreads();

        // ---- MFMA over the 128-K tile ----
        #pragma unroll
        for (int kk = 0; kk < 4; ++kk) {
            const int cb = kk * 4 + (l >> 4);
            bf16x8 af[4], bfr[2];
            #pragma unroll
            for (int m = 0; m < 4; ++m) {
                int row = wm * 64 + m * 16 + (l & 15);
                af[m] = *(const bf16x8*)&Alds[row * 128 + ((cb ^ (row & 15)) << 3)];
            }
            #pragma unroll
            for (int nn = 0; nn < 2; ++nn) {
                int cl = wn * 32 + nn * 16 + (l & 15);
                bfr[nn] = *(const bf16x8*)&Blds[cl * 128 + ((cb ^ (cl & 15)) << 3)];
            }
            #pragma unroll
            for (int m = 0; m < 4; ++m)
                #pragma unroll
                for (int nn = 0; nn < 2; ++nn)
                    acc[m][nn] = __builtin_amdgcn_mfma_f32_16x16x32_bf16(
                        af[m], bfr[nn], acc[m][nn], 0, 0, 0);
        }
        __syncthreads();
    }

    // ---- epilogue: per-wave 64x32 tile -> Cpart[ks] ----
    float* Cb = Cpart + (size_t)ks * (M_TOK * OUT_F);
    #pragma unroll
    for (int m = 0; m < 4; ++m) {
        int row = wm * 64 + m * 16 + ((l >> 4) << 2);
        #pragma unroll
        for (int nn = 0; nn < 2; ++nn) {
            int col = n0 + wn * 32 + nn * 16 + (l & 15);
            #pragma unroll
            for (int r = 0; r < 4; ++r)
                Cb[(size_t)(row + r) * OUT_F + col] = acc[m][nn][r];
        }
    }
}

// ---------------------------------------------------------------------------
// Reduce: out[t][inv_out[c]] = sum_ks Cpart[ks][t][c]
//   coalesced float4 reads, scattered 4B writes (L2 merges lines).
// ---------------------------------------------------------------------------
__global__ __launch_bounds__(256) void k_reduce(const float* __restrict__ Cpart,
                                                const int* __restrict__ inv_out,
                                                float* __restrict__ out) {
    int idx = blockIdx.x * 256 + threadIdx.x;   // 0..131071, 4 cols each
    int t  = idx >> 10;
    int c0 = (idx & 1023) << 2;
    float4 s = make_float4(0.f, 0.f, 0.f, 0.f);
    #pragma unroll
    for (int ks = 0; ks < KSPLIT; ++ks) {
        float4 v = *(const float4*)&Cpart[(size_t)ks * (M_TOK * OUT_F) + (size_t)t * OUT_F + c0];
        s.x += v.x; s.y += v.y; s.z += v.z; s.w += v.w;
    }
    const int* op = &inv_out[c0];
    float* row = out + (size_t)t * OUT_F;
    row[op[0]] = s.x;
    row[op[1]] = s.y;
    row[op[2]] = s.z;
    row[op[3]] = s.w;
}

// ---------------------------------------------------------------------------
extern "C" void kernel_launch(void* const* d_in, const int* in_sizes, int n_in,
                              void* d_out, int out_size, void* d_ws, size_t ws_size,
                              hipStream_t stream) {
    const float* x           = (const float*)d_in[0];
    const int*   qweight     = (const int*)d_in[1];
    const float* alpha       = (const float*)d_in[2];
    const float* beta        = (const float*)d_in[3];
    // d_in[4] = block_bitwidth (uniform 3, unused)
    const int*   offset      = (const int*)d_in[5];
    const int*   in_reorder  = (const int*)d_in[6];
    const int*   out_reorder = (const int*)d_in[7];
    float* out = (float*)d_out;

    // workspace: xr (1MB) | Cpart (16MB) | inv_out (16KB) | A2 (512KB) | B7 (512KB)
    char* ws = (char*)d_ws;
    unsigned short* xr      = (unsigned short*)ws;
    float*          Cpart   = (float*)(ws + (1u << 20));
    int*            inv_out = (int*)(ws + (1u << 20) + (16u << 20));
    float*          A2      = (float*)(ws + (1u << 20) + (16u << 20) + (16u << 10));
    float*          B7      = A2 + NGRP * OUT_F;

    k_prep<<<dim3(644), dim3(256), 0, stream>>>(x, in_reorder, out_reorder,
                                                alpha, beta, xr, inv_out, A2, B7);
    k_fused<<<dim3(64, KSPLIT), dim3(256), 0, stream>>>(xr, qweight, A2, B7, offset, Cpart);
    k_reduce<<<dim3(512), dim3(256), 0, stream>>>(Cpart, inv_out, out);
}